// Round 1
// 681.017 us; speedup vs baseline: 1.0944x; 1.0944x over previous
//
#include <hip/hip_runtime.h>
#include <math.h>

#define Bq 4
#define Nn 4
#define Cc 256
#define Hh 100
#define Ww 152
#define HW (Hh * Ww)          // 15200
#define NMAP (Bq * 5)         // 20 maps: per b: [feat, n0..n3]
#define TILE 32
#define TPB (HW / TILE)       // 475
#define CSPLIT 16
#define CCHUNK (Cc / CSPLIT)  // 16 channels per split; max count 16*9=144 fits u8
#define QPM (HW / 4)          // 3800 quads per map (Ww%4==0 -> quads never straddle rows)

// ws layout (bytes) — unchanged from previous version:
//   s_all : double[NMAP*HW]          @ 0          (2,432,000)
//   thr   : float [NMAP*HW]          @ 2,432,000  (1,216,000)
//   pcnt  : u32   [CSPLIT*Bq*HW]     @ 3,648,000  (3,891,200)  (16 splits x 4-map u8 pack)
//   wt    : float [Bq*Nn*HW]         @ 7,539,200  (  972,800)
//   wT    : float [Cc*Cc]            @ 8,512,000  (  262,144)
#define OFF_SALL 0
#define OFF_THR  2432000
#define OFF_PCNT 3648000
#define OFF_WT   7539200
#define OFF_WTR  8512000

// ---------------------------------------------------------------------------
// K0: transpose w_fuse [o][c] -> wT [c][o]
// ---------------------------------------------------------------------------
__global__ __launch_bounds__(256) void k_wtr(const float* __restrict__ wf,
                                             float* __restrict__ wT) {
    int t = blockIdx.x * blockDim.x + threadIdx.x;
    if (t >= Cc * Cc) return;
    int c = t / Cc, o = t % Cc;
    wT[c * Cc + o] = wf[o * Cc + c];
}

// ---------------------------------------------------------------------------
// K1: per-(map,pixel) channel sum in fp64.
// ---------------------------------------------------------------------------
__global__ __launch_bounds__(256) void k_sums(const float* __restrict__ feat,
                                              const float* __restrict__ nearf,
                                              double* __restrict__ s_all) {
    int t = blockIdx.x * blockDim.x + threadIdx.x;
    if (t >= NMAP * HW) return;
    int m = t / HW, p = t % HW;
    int b = m / 5, r = m % 5;
    const float* src = (r == 0)
        ? (feat + (size_t)b * Cc * HW)
        : (nearf + ((size_t)(b * Nn + (r - 1))) * Cc * HW);
    src += p;
    double a0 = 0, a1 = 0, a2 = 0, a3 = 0;
#pragma unroll 8
    for (int c = 0; c < Cc; c += 4) {
        a0 += (double)src[(size_t)(c + 0) * HW];
        a1 += (double)src[(size_t)(c + 1) * HW];
        a2 += (double)src[(size_t)(c + 2) * HW];
        a3 += (double)src[(size_t)(c + 3) * HW];
    }
    s_all[(size_t)m * HW + p] = (a0 + a1) + (a2 + a3);
}

// ---------------------------------------------------------------------------
// K2: box-9 of channel sums -> fp64 avg -> exact float threshold.
// thr = smallest float >= avg  =>  (v >= thr) in fp32 == ((double)v >= avg).
// ---------------------------------------------------------------------------
__global__ __launch_bounds__(256) void k_thr(const double* __restrict__ s_all,
                                             float* __restrict__ thr) {
    int t = blockIdx.x * blockDim.x + threadIdx.x;
    if (t >= NMAP * HW) return;
    int m = t / HW, p = t % HW;
    int i = p / Ww, j = p % Ww;
    int im = (i > 0) ? i - 1 : 0;
    int ip = (i < Hh - 1) ? i + 1 : Hh - 1;
    int jm = (j > 0) ? j - 1 : 0;
    int jp = (j < Ww - 1) ? j + 1 : Ww - 1;
    const double* s = s_all + (size_t)m * HW;
    double a = s[im * Ww + jm] + s[im * Ww + j] + s[im * Ww + jp]
             + s[i  * Ww + jm] + s[i  * Ww + j] + s[i  * Ww + jp]
             + s[ip * Ww + jm] + s[ip * Ww + j] + s[ip * Ww + jp];
    a *= (1.0 / (9.0 * (double)Cc));
    float f = (float)a;
    if ((double)f < a) f = nextafterf(f, HUGE_VALF);
    thr[(size_t)m * HW + p] = f;
}

// ---------------------------------------------------------------------------
// K3: census partial counts, 4 pixels (one row-quad) per thread.
// Per (channel, map): 3 rows x (1 aligned float4 + 2 clamped edge scalars)
// = 9 load instructions covering all four 3x3 windows (vs 36 scalar before).
// blockIdx.y = channel split (16 ch each). Partial counts <= 144 -> u8 pack,
// 4 maps per u32, one uint4 store per thread.
// ---------------------------------------------------------------------------
__global__ __launch_bounds__(128) void k_census(const float* __restrict__ feat,
                                                const float* __restrict__ nearf,
                                                const float* __restrict__ thr,
                                                unsigned* __restrict__ pcnt) {
    int t = blockIdx.x * blockDim.x + threadIdx.x;
    if (t >= Bq * QPM) return;
    int s = blockIdx.y;
    int b = t / QPM, qd = t % QPM;
    int p0 = qd * 4;
    int i = p0 / Ww, j0 = p0 % Ww;
    int im = (i > 0) ? i - 1 : 0;
    int ip = (i < Hh - 1) ? i + 1 : Hh - 1;
    int jl = (j0 > 0) ? (j0 - 1) : 0;             // clamped left edge col
    int jr = (j0 + 4 < Ww) ? (j0 + 4) : (Ww - 1); // clamped right edge col
    int r0 = im * Ww, r1 = i * Ww, r2 = ip * Ww;

    // thresholds: feat + 4 near maps, 4 pixels each (aligned float4 reads)
    const float* tb = thr + (size_t)(b * 5) * HW + p0;
    float4 tfv = *(const float4*)(tb);
    float tf[4] = {tfv.x, tfv.y, tfv.z, tfv.w};
    float tn[4][4];
#pragma unroll
    for (int n = 0; n < 4; ++n) {
        float4 v4 = *(const float4*)(tb + (size_t)(n + 1) * HW);
        tn[n][0] = v4.x; tn[n][1] = v4.y; tn[n][2] = v4.z; tn[n][3] = v4.w;
    }

    const float* fb = feat + ((size_t)b * Cc + s * CCHUNK) * HW;
    const float* nb = nearf + ((size_t)(b * Nn) * Cc + s * CCHUNK) * HW;

    int cnt[4][4] = {};   // [map][pixel]
    float v[3][6];        // 3 rows x (left, f4.x..f4.w, right)

#pragma unroll 1
    for (int ci = 0; ci < CCHUNK; ++ci) {
        // ---- feat window ----
        {
            const float* fc = fb + (size_t)ci * HW;
            const int rr[3] = {r0, r1, r2};
#pragma unroll
            for (int r = 0; r < 3; ++r) {
                float4 m4 = *(const float4*)(fc + rr[r] + j0);
                v[r][0] = fc[rr[r] + jl];
                v[r][1] = m4.x; v[r][2] = m4.y; v[r][3] = m4.z; v[r][4] = m4.w;
                v[r][5] = fc[rr[r] + jr];
            }
        }
        unsigned mf[4];
#pragma unroll
        for (int q = 0; q < 4; ++q) {
            unsigned m = 0;
#pragma unroll
            for (int r = 0; r < 3; ++r)
#pragma unroll
                for (int d = 0; d < 3; ++d)
                    m |= (unsigned)(v[r][q + d] >= tf[q]) << (r * 3 + d);
            mf[q] = m;
        }
        // ---- 4 near maps, reusing the row buffer ----
#pragma unroll
        for (int n = 0; n < 4; ++n) {
            const float* nc = nb + ((size_t)n * Cc + ci) * HW;
            const int rr[3] = {r0, r1, r2};
#pragma unroll
            for (int r = 0; r < 3; ++r) {
                float4 m4 = *(const float4*)(nc + rr[r] + j0);
                v[r][0] = nc[rr[r] + jl];
                v[r][1] = m4.x; v[r][2] = m4.y; v[r][3] = m4.z; v[r][4] = m4.w;
                v[r][5] = nc[rr[r] + jr];
            }
#pragma unroll
            for (int q = 0; q < 4; ++q) {
                unsigned m = 0;
#pragma unroll
                for (int r = 0; r < 3; ++r)
#pragma unroll
                    for (int d = 0; d < 3; ++d)
                        m |= (unsigned)(v[r][q + d] >= tn[n][q]) << (r * 3 + d);
                cnt[n][q] += 9 - __popc(mf[q] ^ m);
            }
        }
    }

    uint4 pk;
    pk.x = (unsigned)(cnt[0][0] | (cnt[1][0] << 8) | (cnt[2][0] << 16) | (cnt[3][0] << 24));
    pk.y = (unsigned)(cnt[0][1] | (cnt[1][1] << 8) | (cnt[2][1] << 16) | (cnt[3][1] << 24));
    pk.z = (unsigned)(cnt[0][2] | (cnt[1][2] << 8) | (cnt[2][2] << 16) | (cnt[3][2] << 24));
    pk.w = (unsigned)(cnt[0][3] | (cnt[1][3] << 8) | (cnt[2][3] << 16) | (cnt[3][3] << 24));
    *(uint4*)(pcnt + (size_t)s * (Bq * HW) + (size_t)b * HW + p0) = pk;
}

// ---------------------------------------------------------------------------
// K4: reduce 16 packed u8x4 partials -> softmax over N -> weights wt[b][n][p]
// ---------------------------------------------------------------------------
__global__ __launch_bounds__(256) void k_soft(const unsigned* __restrict__ pcnt,
                                              float* __restrict__ wt) {
    int t = blockIdx.x * blockDim.x + threadIdx.x;
    if (t >= Bq * HW) return;
    int s0 = 0, s1 = 0, s2 = 0, s3 = 0;
#pragma unroll
    for (int s = 0; s < CSPLIT; ++s) {
        unsigned a = pcnt[(size_t)s * (Bq * HW) + t];
        s0 += (int)(a & 0xFF);
        s1 += (int)((a >> 8) & 0xFF);
        s2 += (int)((a >> 16) & 0xFF);
        s3 += (int)(a >> 24);
    }
    float c0 = (float)s0, c1 = (float)s1, c2 = (float)s2, c3 = (float)s3;
    float mx = fmaxf(fmaxf(c0, c1), fmaxf(c2, c3));
    float e0 = expf(c0 - mx), e1 = expf(c1 - mx), e2 = expf(c2 - mx), e3 = expf(c3 - mx);
    float rs = 1.0f / (e0 + e1 + e2 + e3);
    int b = t / HW, p = t % HW;
    float* wb = wt + (size_t)b * Nn * HW + p;
    wb[0 * (size_t)HW] = e0 * rs;
    wb[1 * (size_t)HW] = e1 * rs;
    wb[2 * (size_t)HW] = e2 * rs;
    wb[3 * (size_t)HW] = e3 * rs;
}

// ---------------------------------------------------------------------------
// K5: fused = feat + sum_n wt_n*near_n (LDS tile), then out = wT^T @ fused + b.
// Phase A vectorized: thread = (pq = t&7 quad, cg = t>>3 channel-group of 8);
// 40 float4 loads/thread (vs 160 scalar). Same per-element FMA order.
// Phase B unchanged.
// ---------------------------------------------------------------------------
__global__ __launch_bounds__(256) void k_fuse(const float* __restrict__ feat,
                                              const float* __restrict__ nearf,
                                              const float* __restrict__ wt,
                                              const float* __restrict__ wT,
                                              const float* __restrict__ bf,
                                              float* __restrict__ out) {
    __shared__ float fl[Cc * TILE];  // 32 KB, fl[c][px]
    int blk = blockIdx.x;
    int b = blk / TPB;
    int tp = blk % TPB;
    int p0 = tp * TILE;
    int t = threadIdx.x;

    // ---- Phase A: build fused tile (float4 over pixels) ----
    {
        int pq = t & 7;             // quad within tile: px = pq*4 .. pq*4+3
        int cg = t >> 3;            // 0..31, 8 channels each
        int px = pq * 4;
        int pp = p0 + px;
        const float* wb = wt + (size_t)b * Nn * HW + pp;
        float4 w0 = *(const float4*)(wb + 0 * (size_t)HW);
        float4 w1 = *(const float4*)(wb + 1 * (size_t)HW);
        float4 w2 = *(const float4*)(wb + 2 * (size_t)HW);
        float4 w3 = *(const float4*)(wb + 3 * (size_t)HW);
        const float* fb = feat + (size_t)b * Cc * HW + pp;
        const float* nb = nearf + (size_t)b * Nn * Cc * HW + pp;
#pragma unroll
        for (int k = 0; k < 8; ++k) {
            int c = cg * 8 + k;
            float4 vv = *(const float4*)(fb + (size_t)c * HW);
            float4 n0 = *(const float4*)(nb + ((size_t)0 * Cc + c) * HW);
            float4 n1 = *(const float4*)(nb + ((size_t)1 * Cc + c) * HW);
            float4 n2 = *(const float4*)(nb + ((size_t)2 * Cc + c) * HW);
            float4 n3 = *(const float4*)(nb + ((size_t)3 * Cc + c) * HW);
            vv.x += w0.x * n0.x; vv.y += w0.y * n0.y; vv.z += w0.z * n0.z; vv.w += w0.w * n0.w;
            vv.x += w1.x * n1.x; vv.y += w1.y * n1.y; vv.z += w1.z * n1.z; vv.w += w1.w * n1.w;
            vv.x += w2.x * n2.x; vv.y += w2.y * n2.y; vv.z += w2.z * n2.z; vv.w += w2.w * n2.w;
            vv.x += w3.x * n3.x; vv.y += w3.y * n3.y; vv.z += w3.z * n3.z; vv.w += w3.w * n3.w;
            *(float4*)(&fl[c * TILE + px]) = vv;
        }
    }
    __syncthreads();

    // ---- Phase B ----
    {
        int og = t & 63;            // output channel group: o = og*4 + i
        int pg = t >> 6;            // pixel group: px = pg*8 .. pg*8+7
        const float4* wT4 = (const float4*)wT;    // [Cc][Cc/4]
        const float4* flv = (const float4*)fl;    // [Cc][TILE/4]
        float4 acc[4][2];
#pragma unroll
        for (int i = 0; i < 4; ++i) {
            float bi = bf[og * 4 + i];
            acc[i][0] = make_float4(bi, bi, bi, bi);
            acc[i][1] = make_float4(bi, bi, bi, bi);
        }
#pragma unroll 4
        for (int c = 0; c < Cc; ++c) {
            float4 wv = wT4[c * (Cc / 4) + og];
            float4 f0 = flv[c * (TILE / 4) + pg * 2];
            float4 f1 = flv[c * (TILE / 4) + pg * 2 + 1];
#pragma unroll
            for (int i = 0; i < 4; ++i) {
                float wi = (i == 0) ? wv.x : (i == 1) ? wv.y : (i == 2) ? wv.z : wv.w;
                acc[i][0].x += wi * f0.x; acc[i][0].y += wi * f0.y;
                acc[i][0].z += wi * f0.z; acc[i][0].w += wi * f0.w;
                acc[i][1].x += wi * f1.x; acc[i][1].y += wi * f1.y;
                acc[i][1].z += wi * f1.z; acc[i][1].w += wi * f1.w;
            }
        }
#pragma unroll
        for (int i = 0; i < 4; ++i) {
            float* ob = out + ((size_t)b * Cc + og * 4 + i) * HW + p0 + pg * 8;
            *(float4*)(ob + 0) = acc[i][0];
            *(float4*)(ob + 4) = acc[i][1];
        }
    }
}

extern "C" void kernel_launch(void* const* d_in, const int* in_sizes, int n_in,
                              void* d_out, int out_size, void* d_ws, size_t ws_size,
                              hipStream_t stream) {
    const float* feat = (const float*)d_in[0];   // [B,C,H,W]
    const float* nearf = (const float*)d_in[1];  // [B,N,C,H,W]
    const float* wf = (const float*)d_in[2];     // [C,C]
    const float* bf = (const float*)d_in[3];     // [C]
    float* out = (float*)d_out;                  // [B,C,H,W]

    char* ws = (char*)d_ws;
    double* s_all = (double*)(ws + OFF_SALL);
    float* thr = (float*)(ws + OFF_THR);
    unsigned* pcnt = (unsigned*)(ws + OFF_PCNT);
    float* wt = (float*)(ws + OFF_WT);
    float* wT = (float*)(ws + OFF_WTR);

    k_wtr<<<(Cc * Cc + 255) / 256, 256, 0, stream>>>(wf, wT);
    k_sums<<<(NMAP * HW + 255) / 256, 256, 0, stream>>>(feat, nearf, s_all);
    k_thr<<<(NMAP * HW + 255) / 256, 256, 0, stream>>>(s_all, thr);
    {
        dim3 grid((Bq * QPM + 127) / 128, CSPLIT);
        k_census<<<grid, 128, 0, stream>>>(feat, nearf, thr, pcnt);
    }
    k_soft<<<(Bq * HW + 255) / 256, 256, 0, stream>>>(pcnt, wt);
    k_fuse<<<Bq * TPB, 256, 0, stream>>>(feat, nearf, wt, wT, bf, out);
}